// Round 8
// baseline (977.674 us; speedup 1.0000x reference)
//
#include <hip/hip_runtime.h>
#include <hip/hip_bf16.h>

typedef unsigned short u16;
using short8  = __attribute__((ext_vector_type(8))) short;
using floatx4 = __attribute__((ext_vector_type(4))) float;

__device__ inline u16 f2bu(float f) {
    __hip_bfloat16 h = __float2bfloat16(f);
    return __builtin_bit_cast(u16, h);
}
__device__ inline float b2f(u16 u) {
    unsigned v = (unsigned)u << 16;
    return __builtin_bit_cast(float, v);
}
__device__ inline float gelu_f(float v) {
    float u = 1.5957691216f * (v + 0.044715f * v * v * v);
    return v / (1.f + __expf(-u));
}

// async global->LDS, 16B per lane; LDS dest = wave-uniform base + lane*16.
__device__ inline void load16(const u16* g, u16* l) {
    __builtin_amdgcn_global_load_lds(
        (const __attribute__((address_space(1))) void*)g,
        (__attribute__((address_space(3))) void*)l, 16, 0, 0);
}

// ---------------------------------------------------------------- cvt fp32->bf16 (x4)
__global__ void cvt_bf16v(const float4* __restrict__ in, ushort4* __restrict__ out, int n4) {
    int i = blockIdx.x * 256 + threadIdx.x;
    if (i < n4) {
        float4 f = in[i];
        ushort4 r;
        r.x = f2bu(f.x); r.y = f2bu(f.y); r.z = f2bu(f.z); r.w = f2bu(f.w);
        out[i] = r;
    }
}

// ---------------------------------------------------------------- layernorm (row=768)
__global__ __launch_bounds__(256) void layernorm_bf16(
    const float* __restrict__ x, const float* __restrict__ g,
    const float* __restrict__ b, u16* __restrict__ out)
{
    int row = blockIdx.x;
    int tid = threadIdx.x;
    const float* xr = x + (size_t)row * 768;
    float v0 = xr[tid], v1 = xr[tid + 256], v2 = xr[tid + 512];
    float s = v0 + v1 + v2;
    float ss = v0 * v0 + v1 * v1 + v2 * v2;
    for (int off = 1; off < 64; off <<= 1) {
        s  += __shfl_xor(s, off, 64);
        ss += __shfl_xor(ss, off, 64);
    }
    __shared__ float as[4], ass[4];
    int wave = tid >> 6, lane = tid & 63;
    if (lane == 0) { as[wave] = s; ass[wave] = ss; }
    __syncthreads();
    s  = as[0] + as[1] + as[2] + as[3];
    ss = ass[0] + ass[1] + ass[2] + ass[3];
    float mu  = s * (1.0f / 768.0f);
    float var = ss * (1.0f / 768.0f) - mu * mu;
    float rs  = rsqrtf(var + 1e-5f);
    u16* orow = out + (size_t)row * 768;
    orow[tid]       = f2bu((v0 - mu) * rs * g[tid]       + b[tid]);
    orow[tid + 256] = f2bu((v1 - mu) * rs * g[tid + 256] + b[tid + 256]);
    orow[tid + 512] = f2bu((v2 - mu) * rs * g[tid + 512] + b[tid + 512]);
}

// ---------------------------------------------------------------- split-K reduce (2 partials)
// out = (res ? res : out) + bias + P0 + P1   (fp32), over 8192x768
__global__ __launch_bounds__(256) void red2(
    const ushort4* __restrict__ P0, const ushort4* __restrict__ P1,
    const float* __restrict__ bias, const float4* __restrict__ res,
    float4* __restrict__ out)
{
    int i = blockIdx.x * 256 + threadIdx.x;
    int col = (i % 192) * 4;
    ushort4 a = P0[i], b = P1[i];
    float4 o = res ? res[i] : out[i];
    o.x += bias[col + 0] + b2f(a.x) + b2f(b.x);
    o.y += bias[col + 1] + b2f(a.y) + b2f(b.y);
    o.z += bias[col + 2] + b2f(a.z) + b2f(b.z);
    o.w += bias[col + 3] + b2f(a.w) + b2f(b.w);
    out[i] = o;
}

// ---------------------------------------------------------------- GEMM 128x128, single-buffer max-residency
// C[M,N] = A[M,K]*B[N,K]^T. grid (N/128, M/128, splits), block 256.
// 16KB LDS total (10-block LDS cap), global_load_lds staging (XOR-swizzled,
// 0 bank conflicts), XCD-contiguous remap. Latency hidden by many resident
// blocks (m114 implicit overlap), not intra-wave pipelining.
__global__ __launch_bounds__(256, 6) void gemm_lds(
    const u16* __restrict__ A, int lda,
    const u16* __restrict__ B, int ldb,
    int K,
    const float* __restrict__ bias,
    const float* __restrict__ res,
    float* __restrict__ outf, u16* __restrict__ outb,
    u16* __restrict__ parts, size_t pstride,
    int ldc, int act, int splits)
{
    __shared__ u16 lsa[128 * 32];
    __shared__ u16 lsb[128 * 32];

    int tid  = threadIdx.x;
    int wave = tid >> 6, lane = tid & 63;
    int quad = lane >> 4, l16 = lane & 15;
    int wrow = (wave >> 1) * 64;
    int wcol = (wave & 1) * 64;

    int gx = gridDim.x;
    int nblk = gx * gridDim.y;
    int flat = blockIdx.y * gx + blockIdx.x;
    int d = (flat & 7) * (nblk >> 3) + (flat >> 3);
    int m0 = (d / gx) * 128, n0 = (d % gx) * 128;

    int Kper = K / splits;
    int kbeg = blockIdx.z * Kper;

    floatx4 acc[4][4];
    for (int i = 0; i < 4; ++i)
        for (int j = 0; j < 4; ++j)
            acc[i][j] = (floatx4){0.f, 0.f, 0.f, 0.f};

    // staging map: LDS[r][cp] holds global chunk cp ^ ((r>>1)&3) (XOR swizzle)
    int srow = wave * 32 + (lane >> 2);
    int scol = (((lane & 3) ^ ((lane >> 3) & 3))) * 8;
    const u16* ga0 = A + (size_t)(m0 + srow)      * lda + kbeg + scol;
    const u16* ga1 = A + (size_t)(m0 + srow + 16) * lda + kbeg + scol;
    const u16* gb0 = B + (size_t)(n0 + srow)      * ldb + kbeg + scol;
    const u16* gb1 = B + (size_t)(n0 + srow + 16) * ldb + kbeg + scol;
    int lofs = wave * 1024;

    int xq = (quad ^ ((l16 >> 1) & 3)) * 8;

    for (int k0 = 0; k0 < Kper; k0 += 32) {
        __syncthreads();
        load16(ga0, &lsa[lofs]);
        load16(ga1, &lsa[lofs + 512]);
        load16(gb0, &lsb[lofs]);
        load16(gb1, &lsb[lofs + 512]);
        ga0 += 32; ga1 += 32; gb0 += 32; gb1 += 32;
        __syncthreads();

        short8 af[4], bfr[4];
        #pragma unroll
        for (int rb = 0; rb < 4; ++rb) af[rb]  = *(short8*)&lsa[(wrow + rb * 16 + l16) * 32 + xq];
        #pragma unroll
        for (int cb = 0; cb < 4; ++cb) bfr[cb] = *(short8*)&lsb[(wcol + cb * 16 + l16) * 32 + xq];
        #pragma unroll
        for (int rb = 0; rb < 4; ++rb)
            #pragma unroll
            for (int cb = 0; cb < 4; ++cb)
                acc[rb][cb] = __builtin_amdgcn_mfma_f32_16x16x32_bf16(af[rb], bfr[cb], acc[rb][cb], 0, 0, 0);
    }

    u16* pdst = (splits > 1) ? parts + (size_t)blockIdx.z * pstride : nullptr;
    #pragma unroll
    for (int rb = 0; rb < 4; ++rb)
        #pragma unroll
        for (int cb = 0; cb < 4; ++cb)
            #pragma unroll
            for (int r = 0; r < 4; ++r) {
                int row = m0 + wrow + rb * 16 + quad * 4 + r;
                int col = n0 + wcol + cb * 16 + l16;
                float v = acc[rb][cb][r];
                if (splits > 1) {
                    pdst[(size_t)row * ldc + col] = f2bu(v);
                } else {
                    v += bias[col];
                    if (res) v += res[(size_t)row * ldc + col];
                    if (act) v = gelu_f(v);
                    if (outf) outf[(size_t)row * ldc + col] = v;
                    else      outb[(size_t)row * ldc + col] = f2bu(v);
                }
            }
}

// ---------------------------------------------------------------- fused attention
__global__ __launch_bounds__(256) void attn_fused(
    const u16* __restrict__ qkv, u16* __restrict__ o)
{
    const int N = 1024, C3 = 2304;
    int qb = blockIdx.x;
    int bh = blockIdx.y;
    int b = bh / 12, h = bh % 12;
    int tid = threadIdx.x, wave = tid >> 6, lane = tid & 63;
    int quad = lane >> 4, l16 = lane & 15;

    __shared__ u16 lk[64 * 64];
    __shared__ u16 lvt[64][72];
    __shared__ u16 lp[4][16][72];

    const size_t base = (size_t)b * N * C3;
    int q0 = qb * 64 + wave * 16;

    short8 qa0 = *(const short8*)&qkv[base + (size_t)(q0 + l16) * C3 + h * 64 + quad * 8];
    short8 qa1 = *(const short8*)&qkv[base + (size_t)(q0 + l16) * C3 + h * 64 + 32 + quad * 8];

    floatx4 oacc[4];
    for (int i = 0; i < 4; ++i) oacc[i] = (floatx4){0.f, 0.f, 0.f, 0.f};
    float lsum[4] = {0.f, 0.f, 0.f, 0.f};

    for (int kt = 0; kt < N; kt += 64) {
        __syncthreads();
        #pragma unroll
        for (int i = 0; i < 2; ++i) {
            int idx = i * 2048 + wave * 512 + lane * 8;
            int r = idx >> 6;
            int gc = (lane & 7) ^ (r & 7);
            load16(&qkv[base + (size_t)(kt + r) * C3 + 768 + h * 64 + gc * 8], &lk[idx]);
        }
        {
            int key = tid & 63, dbase = (tid >> 6) * 16;
            const u16* vp = &qkv[base + (size_t)(kt + key) * C3 + 1536 + h * 64 + dbase];
            uint4 vv0 = *(const uint4*)vp;
            uint4 vv1 = *(const uint4*)(vp + 8);
            const u16* e0 = (const u16*)&vv0;
            const u16* e1 = (const u16*)&vv1;
            #pragma unroll
            for (int i = 0; i < 8; ++i) {
                lvt[dbase + i][key]     = e0[i];
                lvt[dbase + 8 + i][key] = e1[i];
            }
        }
        __syncthreads();

        float p[4][4];
        #pragma unroll
        for (int kb = 0; kb < 4; ++kb) {
            int R = kb * 16 + l16;
            short8 b0 = *(short8*)&lk[R * 64 + ((quad ^ (R & 7)) * 8)];
            short8 b1 = *(short8*)&lk[R * 64 + (((quad + 4) ^ (R & 7)) * 8)];
            floatx4 c = (floatx4){0.f, 0.f, 0.f, 0.f};
            c = __builtin_amdgcn_mfma_f32_16x16x32_bf16(qa0, b0, c, 0, 0, 0);
            c = __builtin_amdgcn_mfma_f32_16x16x32_bf16(qa1, b1, c, 0, 0, 0);
            #pragma unroll
            for (int r = 0; r < 4; ++r) {
                p[kb][r] = __expf(c[r] * 0.125f);
                lsum[r] += p[kb][r];
            }
        }
        #pragma unroll
        for (int kb = 0; kb < 4; ++kb)
            #pragma unroll
            for (int r = 0; r < 4; ++r)
                lp[wave][quad * 4 + r][kb * 16 + l16] = f2bu(p[kb][r]);

        short8 pa0 = *(short8*)&lp[wave][l16][quad * 8];
        short8 pa1 = *(short8*)&lp[wave][l16][32 + quad * 8];
        #pragma unroll
        for (int db = 0; db < 4; ++db) {
            short8 vb0 = *(short8*)&lvt[db * 16 + l16][quad * 8];
            short8 vb1 = *(short8*)&lvt[db * 16 + l16][32 + quad * 8];
            oacc[db] = __builtin_amdgcn_mfma_f32_16x16x32_bf16(pa0, vb0, oacc[db], 0, 0, 0);
            oacc[db] = __builtin_amdgcn_mfma_f32_16x16x32_bf16(pa1, vb1, oacc[db], 0, 0, 0);
        }
    }

    #pragma unroll
    for (int r = 0; r < 4; ++r)
        for (int off = 1; off < 16; off <<= 1)
            lsum[r] += __shfl_xor(lsum[r], off, 64);

    #pragma unroll
    for (int db = 0; db < 4; ++db)
        #pragma unroll
        for (int r = 0; r < 4; ++r) {
            int row = q0 + quad * 4 + r;
            int col = h * 64 + db * 16 + l16;
            o[(size_t)(b * N + row) * 768 + col] = f2bu(oacc[db][r] / lsum[r]);
        }
}

// ---------------------------------------------------------------- launch
extern "C" void kernel_launch(void* const* d_in, const int* in_sizes, int n_in,
                              void* d_out, int out_size, void* d_ws, size_t ws_size,
                              hipStream_t stream) {
    const float* x      = (const float*)d_in[0];
    const float* n1g    = (const float*)d_in[1];
    const float* n1b    = (const float*)d_in[2];
    const float* qkv_w  = (const float*)d_in[3];
    const float* qkv_b  = (const float*)d_in[4];
    const float* proj_w = (const float*)d_in[5];
    const float* proj_b = (const float*)d_in[6];
    const float* n2g    = (const float*)d_in[7];
    const float* n2b    = (const float*)d_in[8];
    const float* fc1_w  = (const float*)d_in[9];
    const float* fc1_b  = (const float*)d_in[10];
    const float* fc2_w  = (const float*)d_in[11];
    const float* fc2_b  = (const float*)d_in[12];
    float* out = (float*)d_out;

    const int T = 8192;
    char* ws = (char*)d_ws;
    u16* w_qkv  = (u16*)ws;               ws += (size_t)2304 * 768 * 2;
    u16* w_proj = (u16*)ws;               ws += (size_t)768 * 768 * 2;
    u16* w_fc1  = (u16*)ws;               ws += (size_t)3072 * 768 * 2;
    u16* w_fc2  = (u16*)ws;               ws += (size_t)768 * 3072 * 2;
    u16* h_buf  = (u16*)ws;               ws += (size_t)T * 768 * 2;
    u16* qkvbuf = (u16*)ws;               ws += (size_t)T * 2304 * 2;
    u16* o_buf  = (u16*)ws;               ws += (size_t)T * 768 * 2;
    u16* pbuf   = (u16*)ws;               ws += (size_t)T * 768 * 2;   // split-K partial #1
    u16* fc1out = qkvbuf;   // spans qkvbuf+o_buf (both dead at FC1 time)
    bool do_split = (size_t)(ws - (char*)d_ws) <= ws_size;
    size_t pstr = (size_t)(pbuf - h_buf);  // element stride: partial0(h_buf) -> partial1(pbuf)

    cvt_bf16v<<<dim3(2304 * 768 / 4 / 256), 256, 0, stream>>>((const float4*)qkv_w,  (ushort4*)w_qkv,  2304 * 768 / 4);
    cvt_bf16v<<<dim3(768 * 768 / 4 / 256),  256, 0, stream>>>((const float4*)proj_w, (ushort4*)w_proj, 768 * 768 / 4);
    cvt_bf16v<<<dim3(3072 * 768 / 4 / 256), 256, 0, stream>>>((const float4*)fc1_w,  (ushort4*)w_fc1,  3072 * 768 / 4);
    cvt_bf16v<<<dim3(768 * 3072 / 4 / 256), 256, 0, stream>>>((const float4*)fc2_w,  (ushort4*)w_fc2,  768 * 3072 / 4);

    // LN1
    layernorm_bf16<<<dim3(T), 256, 0, stream>>>(x, n1g, n1b, h_buf);
    // QKV (1152 blocks)
    gemm_lds<<<dim3(2304 / 128, T / 128), 256, 0, stream>>>(
        h_buf, 768, w_qkv, 768, 768, qkv_b, nullptr, nullptr, qkvbuf, nullptr, 0, 2304, 0, 1);
    // attention
    attn_fused<<<dim3(16, 96), 256, 0, stream>>>(qkvbuf, o_buf);
    // proj + residual(x) -> out.  Partials: h_buf (LN1 out, dead after QKV) + pbuf.
    if (do_split) {
        gemm_lds<<<dim3(768 / 128, T / 128, 2), 256, 0, stream>>>(
            o_buf, 768, w_proj, 768, 768, proj_b, nullptr, nullptr, nullptr,
            h_buf, pstr, 768, 0, 2);
        red2<<<dim3(T * 768 / 4 / 256), 256, 0, stream>>>(
            (const ushort4*)h_buf, (const ushort4*)pbuf, proj_b, (const float4*)x, (float4*)out);
    } else {
        gemm_lds<<<dim3(768 / 128, T / 128), 256, 0, stream>>>(
            o_buf, 768, w_proj, 768, 768, proj_b, x, out, nullptr, nullptr, 0, 768, 0, 1);
    }
    // LN2
    layernorm_bf16<<<dim3(T), 256, 0, stream>>>(out, n2g, n2b, h_buf);
    // FC1 + GELU (1536 blocks)
    gemm_lds<<<dim3(3072 / 128, T / 128), 256, 0, stream>>>(
        h_buf, 768, w_fc1, 768, 768, fc1_b, nullptr, nullptr, fc1out, nullptr, 0, 3072, 1, 1);
    // FC2 + residual(out in place).  Partials: h_buf (LN2 out, dead after FC1) + pbuf.
    // NOTE: partials must NOT touch o_buf — it is the tail of fc1out (still read as A).
    if (do_split) {
        gemm_lds<<<dim3(768 / 128, T / 128, 2), 256, 0, stream>>>(
            fc1out, 3072, w_fc2, 3072, 3072, fc2_b, nullptr, nullptr, nullptr,
            h_buf, pstr, 768, 0, 2);
        red2<<<dim3(T * 768 / 4 / 256), 256, 0, stream>>>(
            (const ushort4*)h_buf, (const ushort4*)pbuf, fc2_b, nullptr, (float4*)out);
    } else {
        gemm_lds<<<dim3(768 / 128, T / 128), 256, 0, stream>>>(
            fc1out, 3072, w_fc2, 3072, 3072, fc2_b, out, out, nullptr, nullptr, 0, 768, 0, 1);
    }
}

// Round 9
// 418.418 us; speedup vs baseline: 2.3366x; 2.3366x over previous
//
#include <hip/hip_runtime.h>
#include <hip/hip_bf16.h>

typedef unsigned short u16;
using short8  = __attribute__((ext_vector_type(8))) short;
using floatx4 = __attribute__((ext_vector_type(4))) float;

__device__ inline u16 f2bu(float f) {
    __hip_bfloat16 h = __float2bfloat16(f);
    return __builtin_bit_cast(u16, h);
}
__device__ inline float b2f(u16 u) {
    unsigned v = (unsigned)u << 16;
    return __builtin_bit_cast(float, v);
}
__device__ inline float gelu_f(float v) {
    float u = 1.5957691216f * (v + 0.044715f * v * v * v);
    return v / (1.f + __expf(-u));
}

// async global->LDS, 16B per lane; LDS dest = wave-uniform base + lane*16.
__device__ inline void load16(const u16* g, u16* l) {
    __builtin_amdgcn_global_load_lds(
        (const __attribute__((address_space(1))) void*)g,
        (__attribute__((address_space(3))) void*)l, 16, 0, 0);
}

// ---------------------------------------------------------------- cvt fp32->bf16 (x4)
__global__ void cvt_bf16v(const float4* __restrict__ in, ushort4* __restrict__ out, int n4) {
    int i = blockIdx.x * 256 + threadIdx.x;
    if (i < n4) {
        float4 f = in[i];
        ushort4 r;
        r.x = f2bu(f.x); r.y = f2bu(f.y); r.z = f2bu(f.z); r.w = f2bu(f.w);
        out[i] = r;
    }
}

// ---------------------------------------------------------------- layernorm (row=768)
__global__ __launch_bounds__(256) void layernorm_bf16(
    const float* __restrict__ x, const float* __restrict__ g,
    const float* __restrict__ b, u16* __restrict__ out)
{
    int row = blockIdx.x;
    int tid = threadIdx.x;
    const float* xr = x + (size_t)row * 768;
    float v0 = xr[tid], v1 = xr[tid + 256], v2 = xr[tid + 512];
    float s = v0 + v1 + v2;
    float ss = v0 * v0 + v1 * v1 + v2 * v2;
    for (int off = 1; off < 64; off <<= 1) {
        s  += __shfl_xor(s, off, 64);
        ss += __shfl_xor(ss, off, 64);
    }
    __shared__ float as[4], ass[4];
    int wave = tid >> 6, lane = tid & 63;
    if (lane == 0) { as[wave] = s; ass[wave] = ss; }
    __syncthreads();
    s  = as[0] + as[1] + as[2] + as[3];
    ss = ass[0] + ass[1] + ass[2] + ass[3];
    float mu  = s * (1.0f / 768.0f);
    float var = ss * (1.0f / 768.0f) - mu * mu;
    float rs  = rsqrtf(var + 1e-5f);
    u16* orow = out + (size_t)row * 768;
    orow[tid]       = f2bu((v0 - mu) * rs * g[tid]       + b[tid]);
    orow[tid + 256] = f2bu((v1 - mu) * rs * g[tid + 256] + b[tid + 256]);
    orow[tid + 512] = f2bu((v2 - mu) * rs * g[tid + 512] + b[tid + 512]);
}

// ---------------------------------------------------------------- split-K reduce (2 partials)
// out = (res ? res : out) + bias + P0 + P1   (fp32), over 8192x768
__global__ __launch_bounds__(256) void red2(
    const ushort4* __restrict__ P0, const ushort4* __restrict__ P1,
    const float* __restrict__ bias, const float4* __restrict__ res,
    float4* __restrict__ out)
{
    int i = blockIdx.x * 256 + threadIdx.x;
    int col = (i % 192) * 4;
    ushort4 a = P0[i], b = P1[i];
    float4 o = res ? res[i] : out[i];
    o.x += bias[col + 0] + b2f(a.x) + b2f(b.x);
    o.y += bias[col + 1] + b2f(a.y) + b2f(b.y);
    o.z += bias[col + 2] + b2f(a.z) + b2f(b.z);
    o.w += bias[col + 3] + b2f(a.w) + b2f(b.w);
    out[i] = o;
}

// ---------------------------------------------------------------- GEMM 128x128, BK=64 single-buffer
// C[M,N] = A[M,K]*B[N,K]^T. grid (N/128, M/128, splits), block 256.
// 32 MFMA per barrier-drain window (2x the BK=32 structure), LDS 32KB,
// global_load_lds staging with 8-chunk XOR swizzle (chunk = c ^ (row&7),
// conflict-free), XCD-contiguous remap. No waves/EU cap (r8 lesson: acc[4][4]
// = 64 AGPR in the unified file; forcing >3 waves/SIMD spills to scratch).
__global__ __launch_bounds__(256) void gemm_k64(
    const u16* __restrict__ A, int lda,
    const u16* __restrict__ B, int ldb,
    int K,
    const float* __restrict__ bias,
    const float* __restrict__ res,
    float* __restrict__ outf, u16* __restrict__ outb,
    u16* __restrict__ parts, size_t pstride,
    int ldc, int act, int splits)
{
    __shared__ u16 lsa[128 * 64];
    __shared__ u16 lsb[128 * 64];

    int tid  = threadIdx.x;
    int wave = tid >> 6, lane = tid & 63;
    int quad = lane >> 4, l16 = lane & 15;
    int wrow = (wave >> 1) * 64;
    int wcol = (wave & 1) * 64;

    int gx = gridDim.x;
    int nblk = gx * gridDim.y;
    int flat = blockIdx.y * gx + blockIdx.x;
    int d = (flat & 7) * (nblk >> 3) + (flat >> 3);
    int m0 = (d / gx) * 128, n0 = (d % gx) * 128;

    int Kper = K / splits;
    int kbeg = blockIdx.z * Kper;

    floatx4 acc[4][4];
    for (int i = 0; i < 4; ++i)
        for (int j = 0; j < 4; ++j)
            acc[i][j] = (floatx4){0.f, 0.f, 0.f, 0.f};

    // staging: inst j of wave w covers LDS u16 [(j*4+w)*512, +512); lane adds l*8.
    // row r = (j*4+w)*8 + (lane>>3); chunk cp = lane&7 holds global chunk cp^(r&7).
    int rsub = lane >> 3;                       // = r & 7
    int gc   = (lane & 7) ^ rsub;               // global k-chunk staged by this lane
    const u16* gA[4];
    const u16* gB[4];
    #pragma unroll
    for (int j = 0; j < 4; ++j) {
        int r = (j * 4 + wave) * 8 + rsub;
        gA[j] = A + (size_t)(m0 + r) * lda + kbeg + gc * 8;
        gB[j] = B + (size_t)(n0 + r) * ldb + kbeg + gc * 8;
    }

    // read-side swizzled chunks: row R has R&7 == l16&7 (wrow/16-multiples are 8-aligned)
    int xq0 = ((quad)     ^ (l16 & 7)) * 8;     // k-half 0: chunks 0..3 pre-swizzle
    int xq1 = ((quad + 4) ^ (l16 & 7)) * 8;     // k-half 1: chunks 4..7

    for (int k0 = 0; k0 < Kper; k0 += 64) {
        __syncthreads();
        #pragma unroll
        for (int j = 0; j < 4; ++j) {
            load16(gA[j], &lsa[(j * 4 + wave) * 512]);
            gA[j] += 64;
        }
        #pragma unroll
        for (int j = 0; j < 4; ++j) {
            load16(gB[j], &lsb[(j * 4 + wave) * 512]);
            gB[j] += 64;
        }
        __syncthreads();

        short8 af[4], bfr[4];
        // k-half 0
        #pragma unroll
        for (int rb = 0; rb < 4; ++rb) af[rb]  = *(short8*)&lsa[(wrow + rb * 16 + l16) * 64 + xq0];
        #pragma unroll
        for (int cb = 0; cb < 4; ++cb) bfr[cb] = *(short8*)&lsb[(wcol + cb * 16 + l16) * 64 + xq0];
        #pragma unroll
        for (int rb = 0; rb < 4; ++rb)
            #pragma unroll
            for (int cb = 0; cb < 4; ++cb)
                acc[rb][cb] = __builtin_amdgcn_mfma_f32_16x16x32_bf16(af[rb], bfr[cb], acc[rb][cb], 0, 0, 0);
        // k-half 1
        #pragma unroll
        for (int rb = 0; rb < 4; ++rb) af[rb]  = *(short8*)&lsa[(wrow + rb * 16 + l16) * 64 + xq1];
        #pragma unroll
        for (int cb = 0; cb < 4; ++cb) bfr[cb] = *(short8*)&lsb[(wcol + cb * 16 + l16) * 64 + xq1];
        #pragma unroll
        for (int rb = 0; rb < 4; ++rb)
            #pragma unroll
            for (int cb = 0; cb < 4; ++cb)
                acc[rb][cb] = __builtin_amdgcn_mfma_f32_16x16x32_bf16(af[rb], bfr[cb], acc[rb][cb], 0, 0, 0);
    }

    u16* pdst = (splits > 1) ? parts + (size_t)blockIdx.z * pstride : nullptr;
    #pragma unroll
    for (int rb = 0; rb < 4; ++rb)
        #pragma unroll
        for (int cb = 0; cb < 4; ++cb)
            #pragma unroll
            for (int r = 0; r < 4; ++r) {
                int row = m0 + wrow + rb * 16 + quad * 4 + r;
                int col = n0 + wcol + cb * 16 + l16;
                float v = acc[rb][cb][r];
                if (splits > 1) {
                    pdst[(size_t)row * ldc + col] = f2bu(v);
                } else {
                    v += bias[col];
                    if (res) v += res[(size_t)row * ldc + col];
                    if (act) v = gelu_f(v);
                    if (outf) outf[(size_t)row * ldc + col] = v;
                    else      outb[(size_t)row * ldc + col] = f2bu(v);
                }
            }
}

// ---------------------------------------------------------------- fused attention
__global__ __launch_bounds__(256) void attn_fused(
    const u16* __restrict__ qkv, u16* __restrict__ o)
{
    const int N = 1024, C3 = 2304;
    int qb = blockIdx.x;
    int bh = blockIdx.y;
    int b = bh / 12, h = bh % 12;
    int tid = threadIdx.x, wave = tid >> 6, lane = tid & 63;
    int quad = lane >> 4, l16 = lane & 15;

    __shared__ u16 lk[64 * 64];
    __shared__ u16 lvt[64][72];
    __shared__ u16 lp[4][16][72];

    const size_t base = (size_t)b * N * C3;
    int q0 = qb * 64 + wave * 16;

    short8 qa0 = *(const short8*)&qkv[base + (size_t)(q0 + l16) * C3 + h * 64 + quad * 8];
    short8 qa1 = *(const short8*)&qkv[base + (size_t)(q0 + l16) * C3 + h * 64 + 32 + quad * 8];

    floatx4 oacc[4];
    for (int i = 0; i < 4; ++i) oacc[i] = (floatx4){0.f, 0.f, 0.f, 0.f};
    float lsum[4] = {0.f, 0.f, 0.f, 0.f};

    for (int kt = 0; kt < N; kt += 64) {
        __syncthreads();
        #pragma unroll
        for (int i = 0; i < 2; ++i) {
            int idx = i * 2048 + wave * 512 + lane * 8;
            int r = idx >> 6;
            int gc = (lane & 7) ^ (r & 7);
            load16(&qkv[base + (size_t)(kt + r) * C3 + 768 + h * 64 + gc * 8], &lk[idx]);
        }
        {
            int key = tid & 63, dbase = (tid >> 6) * 16;
            const u16* vp = &qkv[base + (size_t)(kt + key) * C3 + 1536 + h * 64 + dbase];
            uint4 vv0 = *(const uint4*)vp;
            uint4 vv1 = *(const uint4*)(vp + 8);
            const u16* e0 = (const u16*)&vv0;
            const u16* e1 = (const u16*)&vv1;
            #pragma unroll
            for (int i = 0; i < 8; ++i) {
                lvt[dbase + i][key]     = e0[i];
                lvt[dbase + 8 + i][key] = e1[i];
            }
        }
        __syncthreads();

        float p[4][4];
        #pragma unroll
        for (int kb = 0; kb < 4; ++kb) {
            int R = kb * 16 + l16;
            short8 b0 = *(short8*)&lk[R * 64 + ((quad ^ (R & 7)) * 8)];
            short8 b1 = *(short8*)&lk[R * 64 + (((quad + 4) ^ (R & 7)) * 8)];
            floatx4 c = (floatx4){0.f, 0.f, 0.f, 0.f};
            c = __builtin_amdgcn_mfma_f32_16x16x32_bf16(qa0, b0, c, 0, 0, 0);
            c = __builtin_amdgcn_mfma_f32_16x16x32_bf16(qa1, b1, c, 0, 0, 0);
            #pragma unroll
            for (int r = 0; r < 4; ++r) {
                p[kb][r] = __expf(c[r] * 0.125f);
                lsum[r] += p[kb][r];
            }
        }
        #pragma unroll
        for (int kb = 0; kb < 4; ++kb)
            #pragma unroll
            for (int r = 0; r < 4; ++r)
                lp[wave][quad * 4 + r][kb * 16 + l16] = f2bu(p[kb][r]);

        short8 pa0 = *(short8*)&lp[wave][l16][quad * 8];
        short8 pa1 = *(short8*)&lp[wave][l16][32 + quad * 8];
        #pragma unroll
        for (int db = 0; db < 4; ++db) {
            short8 vb0 = *(short8*)&lvt[db * 16 + l16][quad * 8];
            short8 vb1 = *(short8*)&lvt[db * 16 + l16][32 + quad * 8];
            oacc[db] = __builtin_amdgcn_mfma_f32_16x16x32_bf16(pa0, vb0, oacc[db], 0, 0, 0);
            oacc[db] = __builtin_amdgcn_mfma_f32_16x16x32_bf16(pa1, vb1, oacc[db], 0, 0, 0);
        }
    }

    #pragma unroll
    for (int r = 0; r < 4; ++r)
        for (int off = 1; off < 16; off <<= 1)
            lsum[r] += __shfl_xor(lsum[r], off, 64);

    #pragma unroll
    for (int db = 0; db < 4; ++db)
        #pragma unroll
        for (int r = 0; r < 4; ++r) {
            int row = q0 + quad * 4 + r;
            int col = h * 64 + db * 16 + l16;
            o[(size_t)(b * N + row) * 768 + col] = f2bu(oacc[db][r] / lsum[r]);
        }
}

// ---------------------------------------------------------------- launch
extern "C" void kernel_launch(void* const* d_in, const int* in_sizes, int n_in,
                              void* d_out, int out_size, void* d_ws, size_t ws_size,
                              hipStream_t stream) {
    const float* x      = (const float*)d_in[0];
    const float* n1g    = (const float*)d_in[1];
    const float* n1b    = (const float*)d_in[2];
    const float* qkv_w  = (const float*)d_in[3];
    const float* qkv_b  = (const float*)d_in[4];
    const float* proj_w = (const float*)d_in[5];
    const float* proj_b = (const float*)d_in[6];
    const float* n2g    = (const float*)d_in[7];
    const float* n2b    = (const float*)d_in[8];
    const float* fc1_w  = (const float*)d_in[9];
    const float* fc1_b  = (const float*)d_in[10];
    const float* fc2_w  = (const float*)d_in[11];
    const float* fc2_b  = (const float*)d_in[12];
    float* out = (float*)d_out;

    const int T = 8192;
    char* ws = (char*)d_ws;
    u16* w_qkv  = (u16*)ws;               ws += (size_t)2304 * 768 * 2;
    u16* w_proj = (u16*)ws;               ws += (size_t)768 * 768 * 2;
    u16* w_fc1  = (u16*)ws;               ws += (size_t)3072 * 768 * 2;
    u16* w_fc2  = (u16*)ws;               ws += (size_t)768 * 3072 * 2;
    u16* h_buf  = (u16*)ws;               ws += (size_t)T * 768 * 2;
    u16* qkvbuf = (u16*)ws;               ws += (size_t)T * 2304 * 2;
    u16* o_buf  = (u16*)ws;               ws += (size_t)T * 768 * 2;
    u16* pbuf   = (u16*)ws;               ws += (size_t)T * 768 * 2;   // split-K partial #1
    u16* fc1out = qkvbuf;   // spans qkvbuf+o_buf (both dead at FC1 time)
    bool do_split = (size_t)(ws - (char*)d_ws) <= ws_size;
    size_t pstr = (size_t)(pbuf - h_buf);  // element stride: partial0(h_buf) -> partial1(pbuf)

    cvt_bf16v<<<dim3(2304 * 768 / 4 / 256), 256, 0, stream>>>((const float4*)qkv_w,  (ushort4*)w_qkv,  2304 * 768 / 4);
    cvt_bf16v<<<dim3(768 * 768 / 4 / 256),  256, 0, stream>>>((const float4*)proj_w, (ushort4*)w_proj, 768 * 768 / 4);
    cvt_bf16v<<<dim3(3072 * 768 / 4 / 256), 256, 0, stream>>>((const float4*)fc1_w,  (ushort4*)w_fc1,  3072 * 768 / 4);
    cvt_bf16v<<<dim3(768 * 3072 / 4 / 256), 256, 0, stream>>>((const float4*)fc2_w,  (ushort4*)w_fc2,  768 * 3072 / 4);

    // LN1
    layernorm_bf16<<<dim3(T), 256, 0, stream>>>(x, n1g, n1b, h_buf);
    // QKV (1152 blocks)
    gemm_k64<<<dim3(2304 / 128, T / 128), 256, 0, stream>>>(
        h_buf, 768, w_qkv, 768, 768, qkv_b, nullptr, nullptr, qkvbuf, nullptr, 0, 2304, 0, 1);
    // attention
    attn_fused<<<dim3(16, 96), 256, 0, stream>>>(qkvbuf, o_buf);
    // proj + residual(x) -> out.  Partials: h_buf (LN1 out, dead after QKV) + pbuf.
    if (do_split) {
        gemm_k64<<<dim3(768 / 128, T / 128, 2), 256, 0, stream>>>(
            o_buf, 768, w_proj, 768, 768, proj_b, nullptr, nullptr, nullptr,
            h_buf, pstr, 768, 0, 2);
        red2<<<dim3(T * 768 / 4 / 256), 256, 0, stream>>>(
            (const ushort4*)h_buf, (const ushort4*)pbuf, proj_b, (const float4*)x, (float4*)out);
    } else {
        gemm_k64<<<dim3(768 / 128, T / 128), 256, 0, stream>>>(
            o_buf, 768, w_proj, 768, 768, proj_b, x, out, nullptr, nullptr, 0, 768, 0, 1);
    }
    // LN2
    layernorm_bf16<<<dim3(T), 256, 0, stream>>>(out, n2g, n2b, h_buf);
    // FC1 + GELU (1536 blocks)
    gemm_k64<<<dim3(3072 / 128, T / 128), 256, 0, stream>>>(
        h_buf, 768, w_fc1, 768, 768, fc1_b, nullptr, nullptr, fc1out, nullptr, 0, 3072, 1, 1);
    // FC2 + residual(out in place).  Partials: h_buf (LN2 out, dead after FC1) + pbuf.
    // NOTE: partials must NOT touch o_buf — it is the tail of fc1out (still read as A).
    if (do_split) {
        gemm_k64<<<dim3(768 / 128, T / 128, 2), 256, 0, stream>>>(
            fc1out, 3072, w_fc2, 3072, 3072, fc2_b, nullptr, nullptr, nullptr,
            h_buf, pstr, 768, 0, 2);
        red2<<<dim3(T * 768 / 4 / 256), 256, 0, stream>>>(
            (const ushort4*)h_buf, (const ushort4*)pbuf, fc2_b, nullptr, (float4*)out);
    } else {
        gemm_k64<<<dim3(768 / 128, T / 128), 256, 0, stream>>>(
            fc1out, 3072, w_fc2, 3072, 3072, fc2_b, out, out, nullptr, nullptr, 0, 768, 0, 1);
    }
}

// Round 10
// 405.373 us; speedup vs baseline: 2.4118x; 1.0322x over previous
//
#include <hip/hip_runtime.h>
#include <hip/hip_bf16.h>

typedef unsigned short u16;
using short8  = __attribute__((ext_vector_type(8))) short;
using floatx4 = __attribute__((ext_vector_type(4))) float;

__device__ inline u16 f2bu(float f) {
    __hip_bfloat16 h = __float2bfloat16(f);
    return __builtin_bit_cast(u16, h);
}
__device__ inline float b2f(u16 u) {
    unsigned v = (unsigned)u << 16;
    return __builtin_bit_cast(float, v);
}
__device__ inline float gelu_f(float v) {
    float u = 1.5957691216f * (v + 0.044715f * v * v * v);
    return v / (1.f + __expf(-u));
}

// async global->LDS, 16B per lane; LDS dest = wave-uniform base + lane*16.
__device__ inline void load16(const u16* g, u16* l) {
    __builtin_amdgcn_global_load_lds(
        (const __attribute__((address_space(1))) void*)g,
        (__attribute__((address_space(3))) void*)l, 16, 0, 0);
}

// ---------------------------------------------------------------- cvt fp32->bf16 (x4)
__global__ void cvt_bf16v(const float4* __restrict__ in, ushort4* __restrict__ out, int n4) {
    int i = blockIdx.x * 256 + threadIdx.x;
    if (i < n4) {
        float4 f = in[i];
        ushort4 r;
        r.x = f2bu(f.x); r.y = f2bu(f.y); r.z = f2bu(f.z); r.w = f2bu(f.w);
        out[i] = r;
    }
}

// ---------------------------------------------------------------- layernorm (row=768)
__global__ __launch_bounds__(256) void layernorm_bf16(
    const float* __restrict__ x, const float* __restrict__ g,
    const float* __restrict__ b, u16* __restrict__ out)
{
    int row = blockIdx.x;
    int tid = threadIdx.x;
    const float* xr = x + (size_t)row * 768;
    float v0 = xr[tid], v1 = xr[tid + 256], v2 = xr[tid + 512];
    float s = v0 + v1 + v2;
    float ss = v0 * v0 + v1 * v1 + v2 * v2;
    for (int off = 1; off < 64; off <<= 1) {
        s  += __shfl_xor(s, off, 64);
        ss += __shfl_xor(ss, off, 64);
    }
    __shared__ float as[4], ass[4];
    int wave = tid >> 6, lane = tid & 63;
    if (lane == 0) { as[wave] = s; ass[wave] = ss; }
    __syncthreads();
    s  = as[0] + as[1] + as[2] + as[3];
    ss = ass[0] + ass[1] + ass[2] + ass[3];
    float mu  = s * (1.0f / 768.0f);
    float var = ss * (1.0f / 768.0f) - mu * mu;
    float rs  = rsqrtf(var + 1e-5f);
    u16* orow = out + (size_t)row * 768;
    orow[tid]       = f2bu((v0 - mu) * rs * g[tid]       + b[tid]);
    orow[tid + 256] = f2bu((v1 - mu) * rs * g[tid + 256] + b[tid + 256]);
    orow[tid + 512] = f2bu((v2 - mu) * rs * g[tid + 512] + b[tid + 512]);
}

// ---------------------------------------------------------------- split-K reduce (2 partials)
// out = (res ? res : out) + bias + P0 + P1   (fp32), over 8192x768
__global__ __launch_bounds__(256) void red2(
    const ushort4* __restrict__ P0, const ushort4* __restrict__ P1,
    const float* __restrict__ bias, const float4* __restrict__ res,
    float4* __restrict__ out)
{
    int i = blockIdx.x * 256 + threadIdx.x;
    int col = (i % 192) * 4;
    ushort4 a = P0[i], b = P1[i];
    float4 o = res ? res[i] : out[i];
    o.x += bias[col + 0] + b2f(a.x) + b2f(b.x);
    o.y += bias[col + 1] + b2f(a.y) + b2f(b.y);
    o.z += bias[col + 2] + b2f(a.z) + b2f(b.z);
    o.w += bias[col + 3] + b2f(a.w) + b2f(b.w);
    out[i] = o;
}

// ---------------------------------------------------------------- fused proj-reduce + LN2
// o_row = x + bias + P0 + P1 -> out (fp32); h = LN(o_row)*g + b -> bf16. Block per row.
__global__ __launch_bounds__(256) void red2_ln(
    const u16* __restrict__ P0, const u16* __restrict__ P1,
    const float* __restrict__ bias, const float* __restrict__ x,
    float* __restrict__ out,
    const float* __restrict__ g, const float* __restrict__ bb,
    u16* __restrict__ h)
{
    int row = blockIdx.x;
    int tid = threadIdx.x;
    size_t base = (size_t)row * 768;
    float v[3];
    float s = 0.f, ss = 0.f;
    #pragma unroll
    for (int j = 0; j < 3; ++j) {
        int col = tid + j * 256;
        size_t idx = base + col;
        float o = x[idx] + bias[col] + b2f(P0[idx]) + b2f(P1[idx]);
        out[idx] = o;
        v[j] = o;
        s += o; ss += o * o;
    }
    for (int off = 1; off < 64; off <<= 1) {
        s  += __shfl_xor(s, off, 64);
        ss += __shfl_xor(ss, off, 64);
    }
    __shared__ float as[4], ass[4];
    int wave = tid >> 6, lane = tid & 63;
    if (lane == 0) { as[wave] = s; ass[wave] = ss; }
    __syncthreads();
    s  = as[0] + as[1] + as[2] + as[3];
    ss = ass[0] + ass[1] + ass[2] + ass[3];
    float mu  = s * (1.0f / 768.0f);
    float var = ss * (1.0f / 768.0f) - mu * mu;
    float rs  = rsqrtf(var + 1e-5f);
    #pragma unroll
    for (int j = 0; j < 3; ++j) {
        int col = tid + j * 256;
        h[base + col] = f2bu((v[j] - mu) * rs * g[col] + bb[col]);
    }
}

// ---------------------------------------------------------------- GEMM 128x128, BK=64 single-buffer
// (r9 structure, best measured: FC1 81us / ~475 TF, MfmaUtil 19%, 0 conflicts)
__global__ __launch_bounds__(256) void gemm_k64(
    const u16* __restrict__ A, int lda,
    const u16* __restrict__ B, int ldb,
    int K,
    const float* __restrict__ bias,
    const float* __restrict__ res,
    float* __restrict__ outf, u16* __restrict__ outb,
    u16* __restrict__ parts, size_t pstride,
    int ldc, int act, int splits)
{
    __shared__ u16 lsa[128 * 64];
    __shared__ u16 lsb[128 * 64];

    int tid  = threadIdx.x;
    int wave = tid >> 6, lane = tid & 63;
    int quad = lane >> 4, l16 = lane & 15;
    int wrow = (wave >> 1) * 64;
    int wcol = (wave & 1) * 64;

    int gx = gridDim.x;
    int nblk = gx * gridDim.y;
    int flat = blockIdx.y * gx + blockIdx.x;
    int d = (flat & 7) * (nblk >> 3) + (flat >> 3);
    int m0 = (d / gx) * 128, n0 = (d % gx) * 128;

    int Kper = K / splits;
    int kbeg = blockIdx.z * Kper;

    floatx4 acc[4][4];
    for (int i = 0; i < 4; ++i)
        for (int j = 0; j < 4; ++j)
            acc[i][j] = (floatx4){0.f, 0.f, 0.f, 0.f};

    int rsub = lane >> 3;
    int gc   = (lane & 7) ^ rsub;
    const u16* gA[4];
    const u16* gB[4];
    #pragma unroll
    for (int j = 0; j < 4; ++j) {
        int r = (j * 4 + wave) * 8 + rsub;
        gA[j] = A + (size_t)(m0 + r) * lda + kbeg + gc * 8;
        gB[j] = B + (size_t)(n0 + r) * ldb + kbeg + gc * 8;
    }

    int xq0 = ((quad)     ^ (l16 & 7)) * 8;
    int xq1 = ((quad + 4) ^ (l16 & 7)) * 8;

    for (int k0 = 0; k0 < Kper; k0 += 64) {
        __syncthreads();
        #pragma unroll
        for (int j = 0; j < 4; ++j) {
            load16(gA[j], &lsa[(j * 4 + wave) * 512]);
            gA[j] += 64;
        }
        #pragma unroll
        for (int j = 0; j < 4; ++j) {
            load16(gB[j], &lsb[(j * 4 + wave) * 512]);
            gB[j] += 64;
        }
        __syncthreads();

        short8 af[4], bfr[4];
        #pragma unroll
        for (int rb = 0; rb < 4; ++rb) af[rb]  = *(short8*)&lsa[(wrow + rb * 16 + l16) * 64 + xq0];
        #pragma unroll
        for (int cb = 0; cb < 4; ++cb) bfr[cb] = *(short8*)&lsb[(wcol + cb * 16 + l16) * 64 + xq0];
        #pragma unroll
        for (int rb = 0; rb < 4; ++rb)
            #pragma unroll
            for (int cb = 0; cb < 4; ++cb)
                acc[rb][cb] = __builtin_amdgcn_mfma_f32_16x16x32_bf16(af[rb], bfr[cb], acc[rb][cb], 0, 0, 0);
        #pragma unroll
        for (int rb = 0; rb < 4; ++rb) af[rb]  = *(short8*)&lsa[(wrow + rb * 16 + l16) * 64 + xq1];
        #pragma unroll
        for (int cb = 0; cb < 4; ++cb) bfr[cb] = *(short8*)&lsb[(wcol + cb * 16 + l16) * 64 + xq1];
        #pragma unroll
        for (int rb = 0; rb < 4; ++rb)
            #pragma unroll
            for (int cb = 0; cb < 4; ++cb)
                acc[rb][cb] = __builtin_amdgcn_mfma_f32_16x16x32_bf16(af[rb], bfr[cb], acc[rb][cb], 0, 0, 0);
    }

    u16* pdst = (splits > 1) ? parts + (size_t)blockIdx.z * pstride : nullptr;
    #pragma unroll
    for (int rb = 0; rb < 4; ++rb)
        #pragma unroll
        for (int cb = 0; cb < 4; ++cb)
            #pragma unroll
            for (int r = 0; r < 4; ++r) {
                int row = m0 + wrow + rb * 16 + quad * 4 + r;
                int col = n0 + wcol + cb * 16 + l16;
                float v = acc[rb][cb][r];
                if (splits > 1) {
                    pdst[(size_t)row * ldc + col] = f2bu(v);
                } else {
                    v += bias[col];
                    if (res) v += res[(size_t)row * ldc + col];
                    if (act) v = gelu_f(v);
                    if (outf) outf[(size_t)row * ldc + col] = v;
                    else      outb[(size_t)row * ldc + col] = f2bu(v);
                }
            }
}

// ---------------------------------------------------------------- fused attention
// qkv: bf16 [8*1024, 2304]; o: bf16 [8*1024, 768]
// grid (8 q-blocks of 128 rows, 96 b*h), block 256; wave = 32 q-rows;
// 32 MFMA per wave per 64-key tile (2x r9), K/V staging halved per output.
__global__ __launch_bounds__(256) void attn_fused(
    const u16* __restrict__ qkv, u16* __restrict__ o)
{
    const int N = 1024, C3 = 2304;
    int qb = blockIdx.x;
    int bh = blockIdx.y;
    int b = bh / 12, h = bh % 12;
    int tid = threadIdx.x, wave = tid >> 6, lane = tid & 63;
    int quad = lane >> 4, l16 = lane & 15;

    __shared__ u16 lk[64 * 64];       // K tile, XOR-swizzled [key][dchunk]
    __shared__ u16 lvt[64][72];       // V^T tile [d][key]
    __shared__ u16 lp[4][32][72];     // per-wave P [qrow(32)][key(64)]

    const size_t base = (size_t)b * N * C3;
    int q0 = qb * 128 + wave * 32;

    short8 qa[2][2];
    #pragma unroll
    for (int rb = 0; rb < 2; ++rb)
        #pragma unroll
        for (int ch = 0; ch < 2; ++ch)
            qa[rb][ch] = *(const short8*)&qkv[base + (size_t)(q0 + rb * 16 + l16) * C3 + h * 64 + ch * 32 + quad * 8];

    floatx4 oacc[2][4];
    #pragma unroll
    for (int i = 0; i < 2; ++i)
        #pragma unroll
        for (int j = 0; j < 4; ++j) oacc[i][j] = (floatx4){0.f, 0.f, 0.f, 0.f};
    float lsum[2][4] = {};

    for (int kt = 0; kt < N; kt += 64) {
        __syncthreads();
        #pragma unroll
        for (int i = 0; i < 2; ++i) {
            int idx = i * 2048 + wave * 512 + lane * 8;
            int r = idx >> 6;
            int gc = (lane & 7) ^ (r & 7);
            load16(&qkv[base + (size_t)(kt + r) * C3 + 768 + h * 64 + gc * 8], &lk[idx]);
        }
        {
            int key = tid & 63, dbase = (tid >> 6) * 16;
            const u16* vp = &qkv[base + (size_t)(kt + key) * C3 + 1536 + h * 64 + dbase];
            uint4 vv0 = *(const uint4*)vp;
            uint4 vv1 = *(const uint4*)(vp + 8);
            const u16* e0 = (const u16*)&vv0;
            const u16* e1 = (const u16*)&vv1;
            #pragma unroll
            for (int i = 0; i < 8; ++i) {
                lvt[dbase + i][key]     = e0[i];
                lvt[dbase + 8 + i][key] = e1[i];
            }
        }
        __syncthreads();

        // S = scale * Q K^T ; P = exp(S)
        #pragma unroll
        for (int kb = 0; kb < 4; ++kb) {
            int R = kb * 16 + l16;
            short8 b0 = *(short8*)&lk[R * 64 + ((quad ^ (R & 7)) * 8)];
            short8 b1 = *(short8*)&lk[R * 64 + (((quad + 4) ^ (R & 7)) * 8)];
            #pragma unroll
            for (int rb = 0; rb < 2; ++rb) {
                floatx4 c = (floatx4){0.f, 0.f, 0.f, 0.f};
                c = __builtin_amdgcn_mfma_f32_16x16x32_bf16(qa[rb][0], b0, c, 0, 0, 0);
                c = __builtin_amdgcn_mfma_f32_16x16x32_bf16(qa[rb][1], b1, c, 0, 0, 0);
                #pragma unroll
                for (int r = 0; r < 4; ++r) {
                    float p = __expf(c[r] * 0.125f);
                    lsum[rb][r] += p;
                    lp[wave][rb * 16 + quad * 4 + r][kb * 16 + l16] = f2bu(p);
                }
            }
        }

        // O += P V   (per-wave lp slice: same-wave RAW ordered by lgkmcnt)
        short8 pa[2][2];
        #pragma unroll
        for (int rb = 0; rb < 2; ++rb) {
            pa[rb][0] = *(short8*)&lp[wave][rb * 16 + l16][quad * 8];
            pa[rb][1] = *(short8*)&lp[wave][rb * 16 + l16][32 + quad * 8];
        }
        #pragma unroll
        for (int db = 0; db < 4; ++db) {
            short8 vb0 = *(short8*)&lvt[db * 16 + l16][quad * 8];
            short8 vb1 = *(short8*)&lvt[db * 16 + l16][32 + quad * 8];
            #pragma unroll
            for (int rb = 0; rb < 2; ++rb) {
                oacc[rb][db] = __builtin_amdgcn_mfma_f32_16x16x32_bf16(pa[rb][0], vb0, oacc[rb][db], 0, 0, 0);
                oacc[rb][db] = __builtin_amdgcn_mfma_f32_16x16x32_bf16(pa[rb][1], vb1, oacc[rb][db], 0, 0, 0);
            }
        }
    }

    #pragma unroll
    for (int rb = 0; rb < 2; ++rb)
        #pragma unroll
        for (int r = 0; r < 4; ++r)
            for (int off = 1; off < 16; off <<= 1)
                lsum[rb][r] += __shfl_xor(lsum[rb][r], off, 64);

    #pragma unroll
    for (int rb = 0; rb < 2; ++rb)
        #pragma unroll
        for (int db = 0; db < 4; ++db)
            #pragma unroll
            for (int r = 0; r < 4; ++r) {
                int row = q0 + rb * 16 + quad * 4 + r;
                int col = h * 64 + db * 16 + l16;
                o[(size_t)(b * N + row) * 768 + col] = f2bu(oacc[rb][db][r] / lsum[rb][r]);
            }
}

// ---------------------------------------------------------------- launch
extern "C" void kernel_launch(void* const* d_in, const int* in_sizes, int n_in,
                              void* d_out, int out_size, void* d_ws, size_t ws_size,
                              hipStream_t stream) {
    const float* x      = (const float*)d_in[0];
    const float* n1g    = (const float*)d_in[1];
    const float* n1b    = (const float*)d_in[2];
    const float* qkv_w  = (const float*)d_in[3];
    const float* qkv_b  = (const float*)d_in[4];
    const float* proj_w = (const float*)d_in[5];
    const float* proj_b = (const float*)d_in[6];
    const float* n2g    = (const float*)d_in[7];
    const float* n2b    = (const float*)d_in[8];
    const float* fc1_w  = (const float*)d_in[9];
    const float* fc1_b  = (const float*)d_in[10];
    const float* fc2_w  = (const float*)d_in[11];
    const float* fc2_b  = (const float*)d_in[12];
    float* out = (float*)d_out;

    const int T = 8192;
    char* ws = (char*)d_ws;
    u16* w_qkv  = (u16*)ws;               ws += (size_t)2304 * 768 * 2;
    u16* w_proj = (u16*)ws;               ws += (size_t)768 * 768 * 2;
    u16* w_fc1  = (u16*)ws;               ws += (size_t)3072 * 768 * 2;
    u16* w_fc2  = (u16*)ws;               ws += (size_t)768 * 3072 * 2;
    u16* h_buf  = (u16*)ws;               ws += (size_t)T * 768 * 2;
    u16* qkvbuf = (u16*)ws;               ws += (size_t)T * 2304 * 2;
    u16* o_buf  = (u16*)ws;               ws += (size_t)T * 768 * 2;
    u16* pbuf   = (u16*)ws;               ws += (size_t)T * 768 * 2;   // split-K partial #1
    u16* fc1out = qkvbuf;   // spans qkvbuf+o_buf (both dead at FC1 time)
    bool do_split = (size_t)(ws - (char*)d_ws) <= ws_size;
    size_t pstr = (size_t)(pbuf - h_buf);  // element stride: partial0(h_buf) -> partial1(pbuf)

    cvt_bf16v<<<dim3(2304 * 768 / 4 / 256), 256, 0, stream>>>((const float4*)qkv_w,  (ushort4*)w_qkv,  2304 * 768 / 4);
    cvt_bf16v<<<dim3(768 * 768 / 4 / 256),  256, 0, stream>>>((const float4*)proj_w, (ushort4*)w_proj, 768 * 768 / 4);
    cvt_bf16v<<<dim3(3072 * 768 / 4 / 256), 256, 0, stream>>>((const float4*)fc1_w,  (ushort4*)w_fc1,  3072 * 768 / 4);
    cvt_bf16v<<<dim3(768 * 3072 / 4 / 256), 256, 0, stream>>>((const float4*)fc2_w,  (ushort4*)w_fc2,  768 * 3072 / 4);

    // LN1
    layernorm_bf16<<<dim3(T), 256, 0, stream>>>(x, n1g, n1b, h_buf);
    // QKV
    gemm_k64<<<dim3(2304 / 128, T / 128), 256, 0, stream>>>(
        h_buf, 768, w_qkv, 768, 768, qkv_b, nullptr, nullptr, qkvbuf, nullptr, 0, 2304, 0, 1);
    // attention (128 q-rows/block)
    attn_fused<<<dim3(8, 96), 256, 0, stream>>>(qkvbuf, o_buf);
    // proj split-K=2 -> partials h_buf,pbuf; fused reduce+residual+LN2 -> out(fp32) + h(bf16)
    if (do_split) {
        gemm_k64<<<dim3(768 / 128, T / 128, 2), 256, 0, stream>>>(
            o_buf, 768, w_proj, 768, 768, proj_b, nullptr, nullptr, nullptr,
            h_buf, pstr, 768, 0, 2);
        red2_ln<<<dim3(T), 256, 0, stream>>>(
            h_buf, pbuf, proj_b, x, out, n2g, n2b, h_buf);
    } else {
        gemm_k64<<<dim3(768 / 128, T / 128), 256, 0, stream>>>(
            o_buf, 768, w_proj, 768, 768, proj_b, x, out, nullptr, nullptr, 0, 768, 0, 1);
        layernorm_bf16<<<dim3(T), 256, 0, stream>>>(out, n2g, n2b, h_buf);
    }
    // FC1 + GELU
    gemm_k64<<<dim3(3072 / 128, T / 128), 256, 0, stream>>>(
        h_buf, 768, w_fc1, 768, 768, fc1_b, nullptr, nullptr, fc1out, nullptr, 0, 3072, 1, 1);
    // FC2 + residual(out in place). Partials: h_buf (dead after FC1) + pbuf.
    // (must NOT touch o_buf — it is the tail of fc1out, still read as A)
    if (do_split) {
        gemm_k64<<<dim3(768 / 128, T / 128, 2), 256, 0, stream>>>(
            fc1out, 3072, w_fc2, 3072, 3072, fc2_b, nullptr, nullptr, nullptr,
            h_buf, pstr, 768, 0, 2);
        red2<<<dim3(T * 768 / 4 / 256), 256, 0, stream>>>(
            (const ushort4*)h_buf, (const ushort4*)pbuf, fc2_b, nullptr, (float4*)out);
    } else {
        gemm_k64<<<dim3(768 / 128, T / 128), 256, 0, stream>>>(
            fc1out, 3072, w_fc2, 3072, 3072, fc2_b, out, out, nullptr, nullptr, 0, 768, 0, 1);
    }
}